// Round 3
// baseline (377.774 us; speedup 1.0000x reference)
//
#include <hip/hip_runtime.h>
#include <hip/hip_bf16.h>

// ModernNCA fused bf16-MFMA pipeline, v3.
// B=512 queries, N=131072 candidates, D=192, H=256, NY=10.
// v3: k_encode rewritten — 512 threads, wave-uniform segment mapping,
// no dynamic register indexing (was scratch-spilling), vectorized gathers.
typedef __bf16 bf16;
typedef __attribute__((ext_vector_type(8))) __bf16 bf16x8;
typedef __attribute__((ext_vector_type(4))) __bf16 bf16x4;
typedef __attribute__((ext_vector_type(4))) float f32x4;

#define NQ     512
#define NC     131072
#define DIM    192
#define NY     10
#define NSLICE 1024          // k_dist blocks; 128 cands each (2 chunks of 64)

// ---------------- workspace layout (bytes) ----------------
#define OFF_W1T 0u                              // 256x192 bf16 = 98304
#define OFF_W2T (OFF_W1T + 98304u)              // 192x256 bf16 = 98304
#define OFF_XE  (OFF_W2T + 98304u)              // 512x192 bf16 = 196608
#define OFF_X2  (OFF_XE + 196608u)              // 512 f32 = 2048
#define OFF_CE  (OFF_X2 + 2048u)                // 131072x192 bf16 = 50331648
#define OFF_C2  (OFF_CE + 50331648u)            // 131072 f32 = 524288
#define OFF_P   (OFF_C2 + 524288u)              // 512x1024x12 f32 = 25165824
// total = 76,417,024 B

// ---------------- K0: weight transpose+cast ----------------
__global__ __launch_bounds__(256) void k_prep(const float* __restrict__ W1,
                                              const float* __restrict__ W2,
                                              bf16* __restrict__ W1T,
                                              bf16* __restrict__ W2T) {
  int idx = blockIdx.x * 256 + threadIdx.x;   // 0..98303
  if (idx < 192 * 256) {
    int k = idx / 256, n = idx % 256;
    W1T[n * 192 + k] = (bf16)W1[idx];         // W1T[n][k], K-contiguous
  } else {
    int i2 = idx - 192 * 256;
    int k = i2 / 192, n = i2 % 192;
    W2T[n * 256 + k] = (bf16)W2[i2];          // W2T[n][k]
  }
}

// ---------------- K1/K2: encode + residual MLP (512 thr, 64 rows) --------
// Wave w (0..7) is a SEGMENT owner in encode (all compile-time indices);
// lane = row. GEMM1: wave w owns hid cols [w*32,w*32+32). GEMM2: 12 tiles
// of 16 cols; wave w owns tile w, even waves also own tile 8+w/2.
__global__ __launch_bounds__(512, 4) void k_encode(
    const float* __restrict__ xn, const int* __restrict__ xc,
    const float* __restrict__ Wn, const float* __restrict__ bn,
    const float* __restrict__ emb, const float* __restrict__ b1,
    const float* __restrict__ b2, const bf16* __restrict__ W1T,
    const bf16* __restrict__ W2T, bf16* __restrict__ oe,
    float* __restrict__ on2) {
  __shared__ alignas(16) bf16 zt[64][200];   // encoded z (192 + pad)
  __shared__ alignas(16) bf16 ht[64][264];   // hidden (256 + pad); reused as ot
  __shared__ float n2l[64];

  const int t = threadIdx.x;
  const int row0 = blockIdx.x * 64;
  const int lane = t & 63, w = t >> 6;       // w = wave/segment 0..7
  const int l15 = lane & 15, q = lane >> 4;

  if (t < 64) n2l[t] = 0.f;

  // ---- encode: wave w -> num feature w (16 cols) + cat half-feature ----
  {
    const int g = row0 + lane;
    // numeric feature f = w: z[f*16+j] = xn[g][f]*Wn[f*16+j] + bn[f*16+j]
    float xv = xn[g * 8 + w];                       // per-lane scalar
    f32x4 wv[4], bv[4];
#pragma unroll
    for (int i = 0; i < 4; i++) {                   // wave-uniform broadcast
      wv[i] = *(const f32x4*)&Wn[w * 16 + i * 4];
      bv[i] = *(const f32x4*)&bn[w * 16 + i * 4];
    }
    bf16x8 p0, p1;
#pragma unroll
    for (int u = 0; u < 8; u++) {
      p0[u] = (bf16)(xv * wv[u >> 2][u & 3] + bv[u >> 2][u & 3]);
      p1[u] = (bf16)(xv * wv[2 + (u >> 2)][u & 3] + bv[2 + (u >> 2)][u & 3]);
    }
    *(bf16x8*)&zt[lane][w * 16] = p0;
    *(bf16x8*)&zt[lane][w * 16 + 8] = p1;
    // categorical: feature c = w>>1, j-half = (w&1)*8
    int c = w >> 1, jh = (w & 1) * 8;
    int cv = xc[g * 4 + c];
    f32x4 e0 = *(const f32x4*)&emb[(c * 100 + cv) * 16 + jh];
    f32x4 e1 = *(const f32x4*)&emb[(c * 100 + cv) * 16 + jh + 4];
    bf16x8 pc;
#pragma unroll
    for (int u = 0; u < 4; u++) { pc[u] = (bf16)e0[u]; pc[4 + u] = (bf16)e1[u]; }
    *(bf16x8*)&zt[lane][128 + c * 16 + jh] = pc;
  }
  __syncthreads();

  // ---- GEMM1: H = relu(Z @ W1 + b1); wave w owns cols [w*32, w*32+32) ----
  {
    f32x4 acc[4][2];
    f32x4 z4 = {0.f, 0.f, 0.f, 0.f};
#pragma unroll
    for (int mi = 0; mi < 4; mi++)
#pragma unroll
      for (int ni = 0; ni < 2; ni++) acc[mi][ni] = z4;
#pragma unroll 2
    for (int kk = 0; kk < 192; kk += 32) {
      bf16x8 a[4], b[2];
#pragma unroll
      for (int mi = 0; mi < 4; mi++)
        a[mi] = *(const bf16x8*)&zt[mi * 16 + l15][kk + q * 8];
#pragma unroll
      for (int ni = 0; ni < 2; ni++)
        b[ni] = *(const bf16x8*)&W1T[(size_t)(w * 32 + ni * 16 + l15) * 192 + kk + q * 8];
#pragma unroll
      for (int mi = 0; mi < 4; mi++)
#pragma unroll
        for (int ni = 0; ni < 2; ni++)
          acc[mi][ni] = __builtin_amdgcn_mfma_f32_16x16x32_bf16(a[mi], b[ni], acc[mi][ni], 0, 0, 0);
    }
#pragma unroll
    for (int ni = 0; ni < 2; ni++) {
      int n = w * 32 + ni * 16 + l15;
      float bb = b1[n];
#pragma unroll
      for (int mi = 0; mi < 4; mi++)
#pragma unroll
        for (int r = 0; r < 4; r++) {
          float h = acc[mi][ni][r] + bb;
          ht[mi * 16 + q * 4 + r][n] = (bf16)(h > 0.f ? h : 0.f);
        }
    }
  }
  __syncthreads();

  // ---- GEMM2 k-loop: acc2 = H @ W2; wave w owns tiles {w} (+ {8+w/2} even) --
  const int nt = (w & 1) ? 1 : 2;            // tiles this wave owns
  int tn[2]; tn[0] = w; tn[1] = 8 + (w >> 1);
  f32x4 acc2[4][2];
  {
    f32x4 z4 = {0.f, 0.f, 0.f, 0.f};
#pragma unroll
    for (int mi = 0; mi < 4; mi++)
#pragma unroll
      for (int ni = 0; ni < 2; ni++) acc2[mi][ni] = z4;
#pragma unroll 2
    for (int kk = 0; kk < 256; kk += 32) {
      bf16x8 a[4], b[2];
#pragma unroll
      for (int mi = 0; mi < 4; mi++)
        a[mi] = *(const bf16x8*)&ht[mi * 16 + l15][kk + q * 8];
      for (int ni = 0; ni < nt; ni++)
        b[ni] = *(const bf16x8*)&W2T[(size_t)(tn[ni] * 16 + l15) * 256 + kk + q * 8];
#pragma unroll
      for (int mi = 0; mi < 4; mi++)
        for (int ni = 0; ni < nt; ni++)
          acc2[mi][ni] = __builtin_amdgcn_mfma_f32_16x16x32_bf16(a[mi], b[ni], acc2[mi][ni], 0, 0, 0);
    }
  }
  __syncthreads();   // all ht A-frag reads done; safe to reuse ht as ot

  // ---- epilogue: v = z + acc2 + b2 -> ot (stride 196: conflict-free), norms --
  bf16* ot = &ht[0][0];   // flat, stride 196 (64*196 = 12544 <= 64*264)
  {
    float nrm[4][4];
#pragma unroll
    for (int mi = 0; mi < 4; mi++)
#pragma unroll
      for (int r = 0; r < 4; r++) nrm[mi][r] = 0.f;
    for (int ni = 0; ni < nt; ni++) {
      int n = tn[ni] * 16 + l15;
      float bb = b2[n];
#pragma unroll
      for (int mi = 0; mi < 4; mi++)
#pragma unroll
        for (int r = 0; r < 4; r++) {
          int rr = mi * 16 + q * 4 + r;
          float v = (float)zt[rr][n] + acc2[mi][ni][r] + bb;
          ot[rr * 196 + n] = (bf16)v;
          nrm[mi][r] += v * v;
        }
    }
#pragma unroll
    for (int mi = 0; mi < 4; mi++)
#pragma unroll
      for (int r = 0; r < 4; r++) {
        float s = nrm[mi][r];
        s += __shfl_xor(s, 1);
        s += __shfl_xor(s, 2);
        s += __shfl_xor(s, 4);
        s += __shfl_xor(s, 8);
        if (l15 == 0) atomicAdd(&n2l[mi * 16 + q * 4 + r], s);
      }
  }
  __syncthreads();

  // ---- coalesced copy-out: ot(stride 196) -> oe(stride 192), 8B granules ---
  {
    uint2* dst = (uint2*)(oe + (size_t)row0 * DIM);   // 48 uint2 per row
#pragma unroll
    for (int j = t; j < 64 * 48; j += 512) {
      int r = j / 48, cc = j - r * 48;
      dst[r * 48 + cc] = *(const uint2*)&ot[r * 196 + cc * 4];
    }
  }
  if (t < 64) on2[row0 + t] = n2l[t];
}

// ---------------- K3: dist + exp + PV, no-max flash ----------------
// 1024 blocks x 256 thr (4 waves). Block owns 128 cands (2 chunks of 64).
// Wave owns 32 queries per query-tile; ET is wave-private -> no barriers
// inside the qt loop. O/l accumulate across chunks in registers.
__global__ __launch_bounds__(256, 3) void k_dist(
    const bf16* __restrict__ xe, const float* __restrict__ x2v,
    const bf16* __restrict__ ce, const float* __restrict__ c2v,
    const float* __restrict__ cy, float* __restrict__ P) {
  __shared__ alignas(16) bf16 ct[64][200];     // chunk encodings (25.6 KB)
  __shared__ alignas(16) bf16 ET[4][32][72];   // per-wave exp tiles (18.4 KB)

  const int t = threadIdx.x;
  const int n0 = blockIdx.x * 128;
  const int lane = t & 63, w = t >> 6;
  const int l15 = lane & 15, q = lane >> 4;

  f32x4 z4 = {0.f, 0.f, 0.f, 0.f};
  f32x4 oacc[4][2];
#pragma unroll
  for (int qt = 0; qt < 4; qt++)
#pragma unroll
    for (int mi = 0; mi < 2; mi++) oacc[qt][mi] = z4;

  for (int c = 0; c < 2; ++c) {
    if (c) __syncthreads();                    // prior chunk's ct reads done
    {
      int r = t >> 2, qu = t & 3;
      const uint4* src = (const uint4*)(ce + (size_t)(n0 + c * 64 + r) * DIM);
      uint4* dst = (uint4*)&ct[r][0];
#pragma unroll
      for (int i = 0; i < 6; i++) dst[qu * 6 + i] = src[qu * 6 + i];
    }
    __syncthreads();

    // per-chunk constants: candidate norms + Y B-frags (col 10 = ones -> l)
    f32x4 c2r[4];
#pragma unroll
    for (int mc = 0; mc < 4; mc++)
      c2r[mc] = *(const f32x4*)&c2v[n0 + c * 64 + mc * 16 + q * 4];
    bf16x8 yf[2];
#pragma unroll
    for (int kb = 0; kb < 2; kb++)
#pragma unroll
      for (int jj = 0; jj < 8; jj++) {
        int cand = n0 + c * 64 + kb * 32 + q * 8 + jj;
        float v = (l15 < 10) ? cy[(size_t)cand * NY + l15]
                             : (l15 == 10 ? 1.f : 0.f);
        yf[kb][jj] = (bf16)v;
      }

    for (int qt = 0; qt < 4; ++qt) {
      const int qbase = qt * 128 + w * 32;
      f32x4 acc[4][2];
#pragma unroll
      for (int mc = 0; mc < 4; mc++)
#pragma unroll
        for (int nq = 0; nq < 2; nq++) acc[mc][nq] = z4;

      // dist GEMM: D[cand][query]; A = ct (LDS), B = xe rows (global, L2-hot)
#pragma unroll 2
      for (int kk = 0; kk < 192; kk += 32) {
        bf16x8 a[4], b[2];
#pragma unroll
        for (int mc = 0; mc < 4; mc++)
          a[mc] = *(const bf16x8*)&ct[mc * 16 + l15][kk + q * 8];
#pragma unroll
        for (int nq = 0; nq < 2; nq++)
          b[nq] = *(const bf16x8*)&xe[(size_t)(qbase + nq * 16 + l15) * DIM + kk + q * 8];
#pragma unroll
        for (int mc = 0; mc < 4; mc++)
#pragma unroll
          for (int nq = 0; nq < 2; nq++)
            acc[mc][nq] = __builtin_amdgcn_mfma_f32_16x16x32_bf16(a[mc], b[nq], acc[mc][nq], 0, 0, 0);
      }

      // epilogue: e = exp(-sqrt(d2)); write wave-private ET (A-frag layout)
      float x2l[2];
#pragma unroll
      for (int nq = 0; nq < 2; nq++) x2l[nq] = x2v[qbase + nq * 16 + l15];
#pragma unroll
      for (int nq = 0; nq < 2; nq++)
#pragma unroll
        for (int mc = 0; mc < 4; mc++) {
          bf16x4 ev;
#pragma unroll
          for (int r = 0; r < 4; r++) {
            float d2 = x2l[nq] + c2r[mc][r] - 2.f * acc[mc][nq][r];
            ev[r] = (bf16)__expf(-sqrtf(fmaxf(d2, 0.f)));
          }
          *(bf16x4*)&ET[w][nq * 16 + l15][mc * 16 + q * 4] = ev;
        }

      // PV: O[32q x 16] += E(32q x 64c) @ Y(64c x 16) — wave-private, no barrier
#pragma unroll
      for (int mi = 0; mi < 2; mi++)
#pragma unroll
        for (int kb = 0; kb < 2; kb++) {
          bf16x8 a = *(const bf16x8*)&ET[w][mi * 16 + l15][kb * 32 + q * 8];
          oacc[qt][mi] = __builtin_amdgcn_mfma_f32_16x16x32_bf16(a, yf[kb], oacc[qt][mi], 0, 0, 0);
        }
    }
  }

  // write partials: P[query][slice][12] = {o[10], l, pad}
  if (l15 < 11) {
#pragma unroll
    for (int qt = 0; qt < 4; qt++)
#pragma unroll
      for (int mi = 0; mi < 2; mi++)
#pragma unroll
        for (int r = 0; r < 4; r++) {
          int query = qt * 128 + w * 32 + mi * 16 + q * 4 + r;
          P[((size_t)query * NSLICE + blockIdx.x) * 12 + l15] = oacc[qt][mi][r];
        }
  }
}

// ---------------- K4: combine (pure sum — no max needed) ----------------
__global__ __launch_bounds__(256) void k_comb(const float* __restrict__ P,
                                              float* __restrict__ out) {
  __shared__ float red[4][11];
  const int t = threadIdx.x;
  const int qy = blockIdx.x;
  const int lane = t & 63, w = t >> 6;

  float s[11];
#pragma unroll
  for (int j = 0; j < 11; j++) s[j] = 0.f;
#pragma unroll
  for (int i = 0; i < 4; i++) {
    const float* p = &P[((size_t)qy * NSLICE + t + 256 * i) * 12];
    f32x4 v0 = *(const f32x4*)&p[0];
    f32x4 v1 = *(const f32x4*)&p[4];
    f32x4 v2 = *(const f32x4*)&p[8];
#pragma unroll
    for (int j = 0; j < 4; j++) s[j] += v0[j];
#pragma unroll
    for (int j = 0; j < 4; j++) s[4 + j] += v1[j];
#pragma unroll
    for (int j = 0; j < 3; j++) s[8 + j] += v2[j];   // p[11] is pad — skip
  }
#pragma unroll
  for (int d = 1; d < 64; d <<= 1)
#pragma unroll
    for (int j = 0; j < 11; j++) s[j] += __shfl_xor(s[j], d);
  if (lane == 0)
#pragma unroll
    for (int j = 0; j < 11; j++) red[w][j] = s[j];
  __syncthreads();
  if (t < 10) {
    float o = red[0][t] + red[1][t] + red[2][t] + red[3][t];
    float l = red[0][10] + red[1][10] + red[2][10] + red[3][10];
    out[qy * NY + t] = o / l;
  }
}

// ---------------- launcher ----------------
extern "C" void kernel_launch(void* const* d_in, const int* in_sizes, int n_in,
                              void* d_out, int out_size, void* d_ws, size_t ws_size,
                              hipStream_t stream) {
  (void)in_sizes; (void)n_in; (void)out_size; (void)ws_size;
  const float* x_num = (const float*)d_in[0];
  const int*   x_cat = (const int*)d_in[1];
  const float* c_num = (const float*)d_in[2];
  const int*   c_cat = (const int*)d_in[3];
  const float* c_y   = (const float*)d_in[4];
  const float* W_num = (const float*)d_in[5];
  const float* b_num = (const float*)d_in[6];
  const float* emb   = (const float*)d_in[7];
  const float* W1    = (const float*)d_in[8];
  const float* b1    = (const float*)d_in[9];
  const float* W2    = (const float*)d_in[10];
  const float* b2    = (const float*)d_in[11];
  float* out = (float*)d_out;

  char* ws = (char*)d_ws;
  bf16*  W1T = (bf16*)(ws + OFF_W1T);
  bf16*  W2T = (bf16*)(ws + OFF_W2T);
  bf16*  xe  = (bf16*)(ws + OFF_XE);
  float* x2v = (float*)(ws + OFF_X2);
  bf16*  ce  = (bf16*)(ws + OFF_CE);
  float* c2v = (float*)(ws + OFF_C2);
  float* P   = (float*)(ws + OFF_P);

  k_prep<<<dim3(384), dim3(256), 0, stream>>>(W1, W2, W1T, W2T);
  k_encode<<<dim3(NQ / 64), dim3(512), 0, stream>>>(
      x_num, x_cat, W_num, b_num, emb, b1, b2, W1T, W2T, xe, x2v);
  k_encode<<<dim3(NC / 64), dim3(512), 0, stream>>>(
      c_num, c_cat, W_num, b_num, emb, b1, b2, W1T, W2T, ce, c2v);
  k_dist<<<dim3(NSLICE), dim3(256), 0, stream>>>(xe, x2v, ce, c2v, c_y, P);
  k_comb<<<dim3(NQ), dim3(256), 0, stream>>>(P, out);
}

// Round 4
// 238.837 us; speedup vs baseline: 1.5817x; 1.5817x over previous
//
#include <hip/hip_runtime.h>
#include <hip/hip_bf16.h>

// ModernNCA fused bf16-MFMA pipeline, v4.
// B=512 queries, N=131072 candidates, D=192, H=256, NY=10.
// v4: k_encode wave-owns-M-rows (1 A-read/k-iter, 2 barriers, no atomics,
// no dynamic reg indexing); W1/W2/query-encodings pre-packed in B-fragment
// plane layout [kplane][n][8] so all B loads are lane-contiguous.
typedef __bf16 bf16;
typedef __attribute__((ext_vector_type(8))) __bf16 bf16x8;
typedef __attribute__((ext_vector_type(4))) __bf16 bf16x4;
typedef __attribute__((ext_vector_type(4))) float f32x4;

#define NQ     512
#define NC     131072
#define DIM    192
#define HID    256
#define NY     10
#define NSLICE 1024          // k_dist blocks; 128 cands each (2 chunks of 64)

// ---------------- workspace layout (bytes) ----------------
#define OFF_W1B 0u                              // 24 planes x 256 x 8 bf16 = 98304
#define OFF_W2B (OFF_W1B + 98304u)              // 32 planes x 192 x 8 bf16 = 98304
#define OFF_XEB (OFF_W2B + 98304u)              // 24 planes x 512 x 8 bf16 = 196608
#define OFF_X2  (OFF_XEB + 196608u)             // 512 f32 = 2048
#define OFF_CE  (OFF_X2 + 2048u)                // 131072x192 bf16 = 50331648
#define OFF_C2  (OFF_CE + 50331648u)            // 131072 f32 = 524288
#define OFF_P   (OFF_C2 + 524288u)              // 512x1024x12 f32 = 25165824
// total = 76,417,024 B (same as v2/v3)

// ---------------- K0: weight cast into B-fragment plane layout ----------
// Plane p = (k>>5)*4 + ((k>>3)&3); element j = k&7.
// W1B[(p*256 + n)*8 + j] = W1[k*256 + n]   (k<192, n<256)
// W2B[(p*192 + n)*8 + j] = W2[k*192 + n]   (k<256, n<192)
__global__ __launch_bounds__(256) void k_prep(const float* __restrict__ W1,
                                              const float* __restrict__ W2,
                                              bf16* __restrict__ W1B,
                                              bf16* __restrict__ W2B) {
  int idx = blockIdx.x * 256 + threadIdx.x;   // 0..98303
  if (idx < 192 * 256) {
    int k = idx / 256, n = idx % 256;
    int p = (k >> 5) * 4 + ((k >> 3) & 3);
    W1B[((size_t)(p * 256 + n)) * 8 + (k & 7)] = (bf16)W1[idx];
  } else {
    int i2 = idx - 192 * 256;
    int k = i2 / 192, n = i2 % 192;
    int p = (k >> 5) * 4 + ((k >> 3) & 3);
    W2B[((size_t)(p * 192 + n)) * 8 + (k & 7)] = (bf16)W2[i2];
  }
}

// ---------------- K1/K2: encode + residual MLP (256 thr, 64 rows) --------
// Wave w owns ROWS [16w,16w+16) for both GEMMs (full N per wave):
// 1 LDS A-read per k-iter, ht wave-private (no GEMM1->GEMM2 barrier),
// in-register norm reduction (no atomics). Only 2 barriers total.
// Output: row-major oe (candidates) OR B-plane xeB (queries).
__global__ __launch_bounds__(256, 3) void k_encode(
    const float* __restrict__ xn, const int* __restrict__ xc,
    const float* __restrict__ Wn, const float* __restrict__ bn,
    const float* __restrict__ emb, const float* __restrict__ b1,
    const float* __restrict__ b2, const bf16* __restrict__ W1B,
    const bf16* __restrict__ W2B, bf16* __restrict__ oe,
    bf16* __restrict__ oeB, float* __restrict__ on2) {
  __shared__ alignas(16) bf16 zt[64][200];   // encoded z (192 + pad) 25.6 KB
  __shared__ alignas(16) bf16 ht[64][216];   // hidden (256->216*? see below) 27.6 KB
  // NOTE: ht row stride 216 holds only cols 0..215 -- but we need 256 cols!
  // GEMM1 writes 256 cols per row; stride must be >=256. Fix: store hidden
  // SPLIT: cols [0,216) in ht, cols [216,256) spill into zt's pad? No --
  // instead ht has stride 216 but we declare the hidden tile as [64][216]
  // and keep the remaining 40 columns... (resolved below: ht2)
  __shared__ alignas(16) bf16 ht2[64][48];   // hidden cols [208,256) pad'd; 6.1 KB

  const int t = threadIdx.x;
  const int row0 = blockIdx.x * 64;
  const int lane = t & 63, w = t >> 6;       // wave 0..3
  const int l15 = lane & 15, q = lane >> 4;

  // ---- encode: wave w -> num features {2w,2w+1} + cat feature w ----
  {
    const int g = row0 + lane;
    float2 xv2 = *(const float2*)&xn[(size_t)g * 8 + 2 * w];
    int cv = xc[g * 4 + w];
#pragma unroll
    for (int f01 = 0; f01 < 2; f01++) {
      int f = 2 * w + f01;
      float xv = f01 ? xv2.y : xv2.x;
      f32x4 wv[4], bv[4];
#pragma unroll
      for (int i = 0; i < 4; i++) {
        wv[i] = *(const f32x4*)&Wn[f * 16 + i * 4];
        bv[i] = *(const f32x4*)&bn[f * 16 + i * 4];
      }
      bf16x8 p0, p1;
#pragma unroll
      for (int u = 0; u < 8; u++) {
        p0[u] = (bf16)(xv * wv[u >> 2][u & 3] + bv[u >> 2][u & 3]);
        p1[u] = (bf16)(xv * wv[2 + (u >> 2)][u & 3] + bv[2 + (u >> 2)][u & 3]);
      }
      *(bf16x8*)&zt[lane][f * 16] = p0;
      *(bf16x8*)&zt[lane][f * 16 + 8] = p1;
    }
    const float* er = &emb[(size_t)(w * 100 + cv) * 16];
    f32x4 e0 = *(const f32x4*)&er[0];
    f32x4 e1 = *(const f32x4*)&er[4];
    f32x4 e2 = *(const f32x4*)&er[8];
    f32x4 e3 = *(const f32x4*)&er[12];
    bf16x8 pc0, pc1;
#pragma unroll
    for (int u = 0; u < 4; u++) {
      pc0[u] = (bf16)e0[u]; pc0[4 + u] = (bf16)e1[u];
      pc1[u] = (bf16)e2[u]; pc1[4 + u] = (bf16)e3[u];
    }
    *(bf16x8*)&zt[lane][128 + w * 16] = pc0;
    *(bf16x8*)&zt[lane][128 + w * 16 + 8] = pc1;
  }
  __syncthreads();

  // ---- GEMM1: H = relu(Z @ W1 + b1); wave w rows [16w,16w+16), all 256 n --
  {
    f32x4 acc1[16];
    f32x4 z4 = {0.f, 0.f, 0.f, 0.f};
#pragma unroll
    for (int ni = 0; ni < 16; ni++) acc1[ni] = z4;
#pragma unroll 1
    for (int kk = 0; kk < 192; kk += 32) {
      bf16x8 a = *(const bf16x8*)&zt[w * 16 + l15][kk + q * 8];
      const bf16* wp = &W1B[(size_t)(((kk >> 5) * 4 + q) * 256 + l15) * 8];
      bf16x8 b[16];
#pragma unroll
      for (int ni = 0; ni < 16; ni++)
        b[ni] = *(const bf16x8*)&wp[ni * 128];   // (ni*16)*8
#pragma unroll
      for (int ni = 0; ni < 16; ni++)
        acc1[ni] = __builtin_amdgcn_mfma_f32_16x16x32_bf16(a, b[ni], acc1[ni], 0, 0, 0);
    }
    // write hidden: cols [0,208) -> ht, cols [208,256) -> ht2
#pragma unroll
    for (int ni = 0; ni < 16; ni++) {
      int n = ni * 16 + l15;
      float bb = b1[n];
#pragma unroll
      for (int r = 0; r < 4; r++) {
        float h = acc1[ni][r] + bb;
        bf16 hv = (bf16)(h > 0.f ? h : 0.f);
        int rr = w * 16 + q * 4 + r;
        if (n < 208) ht[rr][n] = hv;
        else         ht2[rr][n - 208] = hv;
      }
    }
  }
  // no barrier: ht rows [16w,16w+16) are wave-private

  // ---- GEMM2: acc2 = H @ W2; wave w rows [16w,16w+16), all 192 n ----
  f32x4 acc2[12];
  {
    f32x4 z4 = {0.f, 0.f, 0.f, 0.f};
#pragma unroll
    for (int ni = 0; ni < 12; ni++) acc2[ni] = z4;
#pragma unroll 1
    for (int kk = 0; kk < 256; kk += 32) {
      int c0 = kk + q * 8;
      bf16x8 a;
      if (c0 < 208) a = *(const bf16x8*)&ht[w * 16 + l15][c0];
      else          a = *(const bf16x8*)&ht2[w * 16 + l15][c0 - 208];
      const bf16* wp = &W2B[(size_t)(((kk >> 5) * 4 + q) * 192 + l15) * 8];
      bf16x8 b[12];
#pragma unroll
      for (int ni = 0; ni < 12; ni++)
        b[ni] = *(const bf16x8*)&wp[ni * 128];
#pragma unroll
      for (int ni = 0; ni < 12; ni++)
        acc2[ni] = __builtin_amdgcn_mfma_f32_16x16x32_bf16(a, b[ni], acc2[ni], 0, 0, 0);
    }
  }

  // ---- epilogue: v = z + acc2 + b2 -> ot (=ht rows, wave-private), norms --
  {
    float nrm[4] = {0.f, 0.f, 0.f, 0.f};
#pragma unroll
    for (int ni = 0; ni < 12; ni++) {
      int n = ni * 16 + l15;
      float bb = b2[n];
#pragma unroll
      for (int r = 0; r < 4; r++) {
        int rr = w * 16 + q * 4 + r;
        float v = (float)zt[rr][n] + acc2[ni][r] + bb;
        ht[rr][n] = (bf16)v;      // reuse ht as output tile (cols 0..191)
        nrm[r] += v * v;
      }
    }
#pragma unroll
    for (int r = 0; r < 4; r++) {
      float s = nrm[r];
      s += __shfl_xor(s, 1);
      s += __shfl_xor(s, 2);
      s += __shfl_xor(s, 4);
      s += __shfl_xor(s, 8);
      if (l15 == 0) on2[row0 + w * 16 + q * 4 + r] = s;
    }
  }
  __syncthreads();

  // ---- copy-out ----
  if (oeB) {
    // queries: B-plane layout xeB[(cc*512 + row)*8 + j], cc = col/8
    for (int cc = w; cc < 24; cc += 4) {
      bf16x8 v = *(const bf16x8*)&ht[lane][cc * 8];
      *(bf16x8*)&oeB[((size_t)cc * NQ + row0 + lane) * 8] = v;
    }
  } else {
    // candidates: row-major
    uint2* dst = (uint2*)(oe + (size_t)row0 * DIM);   // 48 uint2 per row
#pragma unroll
    for (int j = t; j < 64 * 48; j += 256) {
      int r = j / 48, cc = j - r * 48;
      dst[r * 48 + cc] = *(const uint2*)&ht[r][cc * 4];
    }
  }
}

// ---------------- K3: dist + exp + PV, no-max flash ----------------
// 1024 blocks x 256 thr (4 waves). Block owns 128 cands (2 chunks of 64).
// Wave owns 32 queries per query-tile; ET is wave-private -> no barriers
// inside the qt loop. Query encodings read coalesced from B-plane xeB.
__global__ __launch_bounds__(256, 3) void k_dist(
    const bf16* __restrict__ xeB, const float* __restrict__ x2v,
    const bf16* __restrict__ ce, const float* __restrict__ c2v,
    const float* __restrict__ cy, float* __restrict__ P) {
  __shared__ alignas(16) bf16 ct[64][200];     // chunk encodings (25.6 KB)
  __shared__ alignas(16) bf16 ET[4][32][72];   // per-wave exp tiles (18.4 KB)

  const int t = threadIdx.x;
  const int n0 = blockIdx.x * 128;
  const int lane = t & 63, w = t >> 6;
  const int l15 = lane & 15, q = lane >> 4;

  f32x4 z4 = {0.f, 0.f, 0.f, 0.f};
  f32x4 oacc[4][2];
#pragma unroll
  for (int qt = 0; qt < 4; qt++)
#pragma unroll
    for (int mi = 0; mi < 2; mi++) oacc[qt][mi] = z4;

  for (int c = 0; c < 2; ++c) {
    if (c) __syncthreads();                    // prior chunk's ct reads done
    {
      int r = t >> 2, qu = t & 3;
      const uint4* src = (const uint4*)(ce + (size_t)(n0 + c * 64 + r) * DIM);
      uint4* dst = (uint4*)&ct[r][0];
#pragma unroll
      for (int i = 0; i < 6; i++) dst[qu * 6 + i] = src[qu * 6 + i];
    }
    __syncthreads();

    // per-chunk constants: candidate norms + Y B-frags (col 10 = ones -> l)
    f32x4 c2r[4];
#pragma unroll
    for (int mc = 0; mc < 4; mc++)
      c2r[mc] = *(const f32x4*)&c2v[n0 + c * 64 + mc * 16 + q * 4];
    bf16x8 yf[2];
#pragma unroll
    for (int kb = 0; kb < 2; kb++)
#pragma unroll
      for (int jj = 0; jj < 8; jj++) {
        int cand = n0 + c * 64 + kb * 32 + q * 8 + jj;
        float v = (l15 < 10) ? cy[(size_t)cand * NY + l15]
                             : (l15 == 10 ? 1.f : 0.f);
        yf[kb][jj] = (bf16)v;
      }

    for (int qt = 0; qt < 4; ++qt) {
      const int qbase = qt * 128 + w * 32;
      f32x4 acc[4][2];
#pragma unroll
      for (int mc = 0; mc < 4; mc++)
#pragma unroll
        for (int nq = 0; nq < 2; nq++) acc[mc][nq] = z4;

      // dist GEMM: A = ct (LDS), B = xeB planes (global, coalesced)
#pragma unroll 2
      for (int kk = 0; kk < 192; kk += 32) {
        bf16x8 a[4], b[2];
#pragma unroll
        for (int mc = 0; mc < 4; mc++)
          a[mc] = *(const bf16x8*)&ct[mc * 16 + l15][kk + q * 8];
        const bf16* xp = &xeB[(size_t)(((kk >> 5) * 4 + q) * NQ + qbase + l15) * 8];
#pragma unroll
        for (int nq = 0; nq < 2; nq++)
          b[nq] = *(const bf16x8*)&xp[nq * 128];
#pragma unroll
        for (int mc = 0; mc < 4; mc++)
#pragma unroll
          for (int nq = 0; nq < 2; nq++)
            acc[mc][nq] = __builtin_amdgcn_mfma_f32_16x16x32_bf16(a[mc], b[nq], acc[mc][nq], 0, 0, 0);
      }

      // epilogue: e = exp(-sqrt(d2)); write wave-private ET (A-frag layout)
      float x2l[2];
#pragma unroll
      for (int nq = 0; nq < 2; nq++) x2l[nq] = x2v[qbase + nq * 16 + l15];
#pragma unroll
      for (int nq = 0; nq < 2; nq++)
#pragma unroll
        for (int mc = 0; mc < 4; mc++) {
          bf16x4 ev;
#pragma unroll
          for (int r = 0; r < 4; r++) {
            float d2 = x2l[nq] + c2r[mc][r] - 2.f * acc[mc][nq][r];
            ev[r] = (bf16)__expf(-sqrtf(fmaxf(d2, 0.f)));
          }
          *(bf16x4*)&ET[w][nq * 16 + l15][mc * 16 + q * 4] = ev;
        }

      // PV: O[32q x 16] += E(32q x 64c) @ Y(64c x 16) — wave-private
#pragma unroll
      for (int mi = 0; mi < 2; mi++)
#pragma unroll
        for (int kb = 0; kb < 2; kb++) {
          bf16x8 a = *(const bf16x8*)&ET[w][mi * 16 + l15][kb * 32 + q * 8];
          oacc[qt][mi] = __builtin_amdgcn_mfma_f32_16x16x32_bf16(a, yf[kb], oacc[qt][mi], 0, 0, 0);
        }
    }
  }

  // write partials: P[query][slice][12] = {o[10], l, pad}
  if (l15 < 11) {
#pragma unroll
    for (int qt = 0; qt < 4; qt++)
#pragma unroll
      for (int mi = 0; mi < 2; mi++)
#pragma unroll
        for (int r = 0; r < 4; r++) {
          int query = qt * 128 + w * 32 + mi * 16 + q * 4 + r;
          P[((size_t)query * NSLICE + blockIdx.x) * 12 + l15] = oacc[qt][mi][r];
        }
  }
}

// ---------------- K4: combine (pure sum — no max needed) ----------------
__global__ __launch_bounds__(256) void k_comb(const float* __restrict__ P,
                                              float* __restrict__ out) {
  __shared__ float red[4][11];
  const int t = threadIdx.x;
  const int qy = blockIdx.x;
  const int lane = t & 63, w = t >> 6;

  float s[11];
#pragma unroll
  for (int j = 0; j < 11; j++) s[j] = 0.f;
#pragma unroll
  for (int i = 0; i < 4; i++) {
    const float* p = &P[((size_t)qy * NSLICE + t + 256 * i) * 12];
    f32x4 v0 = *(const f32x4*)&p[0];
    f32x4 v1 = *(const f32x4*)&p[4];
    f32x4 v2 = *(const f32x4*)&p[8];
#pragma unroll
    for (int j = 0; j < 4; j++) s[j] += v0[j];
#pragma unroll
    for (int j = 0; j < 4; j++) s[4 + j] += v1[j];
#pragma unroll
    for (int j = 0; j < 3; j++) s[8 + j] += v2[j];   // p[11] is pad — skip
  }
#pragma unroll
  for (int d = 1; d < 64; d <<= 1)
#pragma unroll
    for (int j = 0; j < 11; j++) s[j] += __shfl_xor(s[j], d);
  if (lane == 0)
#pragma unroll
    for (int j = 0; j < 11; j++) red[w][j] = s[j];
  __syncthreads();
  if (t < 10) {
    float o = red[0][t] + red[1][t] + red[2][t] + red[3][t];
    float l = red[0][10] + red[1][10] + red[2][10] + red[3][10];
    out[qy * NY + t] = o / l;
  }
}

// ---------------- launcher ----------------
extern "C" void kernel_launch(void* const* d_in, const int* in_sizes, int n_in,
                              void* d_out, int out_size, void* d_ws, size_t ws_size,
                              hipStream_t stream) {
  (void)in_sizes; (void)n_in; (void)out_size; (void)ws_size;
  const float* x_num = (const float*)d_in[0];
  const int*   x_cat = (const int*)d_in[1];
  const float* c_num = (const float*)d_in[2];
  const int*   c_cat = (const int*)d_in[3];
  const float* c_y   = (const float*)d_in[4];
  const float* W_num = (const float*)d_in[5];
  const float* b_num = (const float*)d_in[6];
  const float* emb   = (const float*)d_in[7];
  const float* W1    = (const float*)d_in[8];
  const float* b1    = (const float*)d_in[9];
  const float* W2    = (const float*)d_in[10];
  const float* b2    = (const float*)d_in[11];
  float* out = (float*)d_out;

  char* ws = (char*)d_ws;
  bf16*  W1B = (bf16*)(ws + OFF_W1B);
  bf16*  W2B = (bf16*)(ws + OFF_W2B);
  bf16*  xeB = (bf16*)(ws + OFF_XEB);
  float* x2v = (float*)(ws + OFF_X2);
  bf16*  ce  = (bf16*)(ws + OFF_CE);
  float* c2v = (float*)(ws + OFF_C2);
  float* P   = (float*)(ws + OFF_P);

  k_prep<<<dim3(384), dim3(256), 0, stream>>>(W1, W2, W1B, W2B);
  k_encode<<<dim3(NQ / 64), dim3(256), 0, stream>>>(
      x_num, x_cat, W_num, b_num, emb, b1, b2, W1B, W2B, nullptr, xeB, x2v);
  k_encode<<<dim3(NC / 64), dim3(256), 0, stream>>>(
      c_num, c_cat, W_num, b_num, emb, b1, b2, W1B, W2B, ce, nullptr, c2v);
  k_dist<<<dim3(NSLICE), dim3(256), 0, stream>>>(xeB, x2v, ce, c2v, c_y, P);
  k_comb<<<dim3(NQ), dim3(256), 0, stream>>>(P, out);
}

// Round 5
// 222.082 us; speedup vs baseline: 1.7011x; 1.0754x over previous
//
#include <hip/hip_runtime.h>
#include <hip/hip_bf16.h>

// ModernNCA fused bf16-MFMA pipeline, v5.
// B=512 queries, N=131072 candidates, D=192, H=256, NY=10.
// v5: k_encode N-split across waves (each W line loaded once per block,
// cuts 1.57 GB L2 weight traffic to 393 MB); k_dist nq=4 (64 q/wave/qt,
// half the A-LDS reads and qt overhead), epilogue+PV in 32-q halves.
typedef __bf16 bf16;
typedef __attribute__((ext_vector_type(8))) __bf16 bf16x8;
typedef __attribute__((ext_vector_type(4))) __bf16 bf16x4;
typedef __attribute__((ext_vector_type(4))) float f32x4;

#define NQ     512
#define NC     131072
#define DIM    192
#define HID    256
#define NY     10
#define NSLICE 1024          // k_dist blocks; 128 cands each (2 chunks of 64)

// ---------------- workspace layout (bytes) ----------------
#define OFF_W1B 0u                              // 24 planes x 256 x 8 bf16 = 98304
#define OFF_W2B (OFF_W1B + 98304u)              // 32 planes x 192 x 8 bf16 = 98304
#define OFF_XEB (OFF_W2B + 98304u)              // 24 planes x 512 x 8 bf16 = 196608
#define OFF_X2  (OFF_XEB + 196608u)             // 512 f32 = 2048
#define OFF_CE  (OFF_X2 + 2048u)                // 131072x192 bf16 = 50331648
#define OFF_C2  (OFF_CE + 50331648u)            // 131072 f32 = 524288
#define OFF_P   (OFF_C2 + 524288u)              // 512x1024x12 f32 = 25165824

// ---------------- K0: weight cast into B-fragment plane layout ----------
// Plane p = (k>>5)*4 + ((k>>3)&3); element j = k&7.
__global__ __launch_bounds__(256) void k_prep(const float* __restrict__ W1,
                                              const float* __restrict__ W2,
                                              bf16* __restrict__ W1B,
                                              bf16* __restrict__ W2B) {
  int idx = blockIdx.x * 256 + threadIdx.x;   // 0..98303
  if (idx < 192 * 256) {
    int k = idx / 256, n = idx % 256;
    int p = (k >> 5) * 4 + ((k >> 3) & 3);
    W1B[((size_t)(p * 256 + n)) * 8 + (k & 7)] = (bf16)W1[idx];
  } else {
    int i2 = idx - 192 * 256;
    int k = i2 / 192, n = i2 % 192;
    int p = (k >> 5) * 4 + ((k >> 3) & 3);
    W2B[((size_t)(p * 192 + n)) * 8 + (k & 7)] = (bf16)W2[i2];
  }
}

// ---------------- K1/K2: encode + residual MLP (256 thr, 64 rows) --------
// Encode: wave w owns features {2w,2w+1} + cat w (all uniform indices).
// GEMM1: wave w owns hid cols [64w,64w+64) — each W1 line loaded ONCE/block.
// GEMM2: wave w owns out cols [48w,48w+48). Residual in-place in zt.
__global__ __launch_bounds__(256, 2) void k_encode(
    const float* __restrict__ xn, const int* __restrict__ xc,
    const float* __restrict__ Wn, const float* __restrict__ bn,
    const float* __restrict__ emb, const float* __restrict__ b1,
    const float* __restrict__ b2, const bf16* __restrict__ W1B,
    const bf16* __restrict__ W2B, bf16* __restrict__ oe,
    bf16* __restrict__ oeB, float* __restrict__ on2) {
  __shared__ alignas(16) bf16 zt[64][200];   // encoded z / output (25.6 KB)
  __shared__ alignas(16) bf16 ht[64][264];   // hidden 256 + pad (33.8 KB)
  __shared__ float n2l[64];

  const int t = threadIdx.x;
  const int row0 = blockIdx.x * 64;
  const int lane = t & 63, w = t >> 6;       // wave 0..3
  const int l15 = lane & 15, q = lane >> 4;

  if (t < 64) n2l[t] = 0.f;

  // ---- encode: wave w -> num features {2w,2w+1} + cat feature w ----
  {
    const int g = row0 + lane;
    float2 xv2 = *(const float2*)&xn[(size_t)g * 8 + 2 * w];
    int cv = xc[g * 4 + w];
#pragma unroll
    for (int f01 = 0; f01 < 2; f01++) {
      int f = 2 * w + f01;
      float xv = f01 ? xv2.y : xv2.x;
      f32x4 wv[4], bv[4];
#pragma unroll
      for (int i = 0; i < 4; i++) {
        wv[i] = *(const f32x4*)&Wn[f * 16 + i * 4];
        bv[i] = *(const f32x4*)&bn[f * 16 + i * 4];
      }
      bf16x8 p0, p1;
#pragma unroll
      for (int u = 0; u < 8; u++) {
        p0[u] = (bf16)(xv * wv[u >> 2][u & 3] + bv[u >> 2][u & 3]);
        p1[u] = (bf16)(xv * wv[2 + (u >> 2)][u & 3] + bv[2 + (u >> 2)][u & 3]);
      }
      *(bf16x8*)&zt[lane][f * 16] = p0;
      *(bf16x8*)&zt[lane][f * 16 + 8] = p1;
    }
    const float* er = &emb[(size_t)(w * 100 + cv) * 16];
    f32x4 e0 = *(const f32x4*)&er[0];
    f32x4 e1 = *(const f32x4*)&er[4];
    f32x4 e2 = *(const f32x4*)&er[8];
    f32x4 e3 = *(const f32x4*)&er[12];
    bf16x8 pc0, pc1;
#pragma unroll
    for (int u = 0; u < 4; u++) {
      pc0[u] = (bf16)e0[u]; pc0[4 + u] = (bf16)e1[u];
      pc1[u] = (bf16)e2[u]; pc1[4 + u] = (bf16)e3[u];
    }
    *(bf16x8*)&zt[lane][128 + w * 16] = pc0;
    *(bf16x8*)&zt[lane][128 + w * 16 + 8] = pc1;
  }
  __syncthreads();

  // ---- GEMM1: H = relu(Z @ W1 + b1); wave w owns n in [64w, 64w+64) ----
  {
    f32x4 acc1[4][4];          // [mi][ni]
    f32x4 z4 = {0.f, 0.f, 0.f, 0.f};
#pragma unroll
    for (int mi = 0; mi < 4; mi++)
#pragma unroll
      for (int ni = 0; ni < 4; ni++) acc1[mi][ni] = z4;
#pragma unroll 2
    for (int kk = 0; kk < 192; kk += 32) {
      bf16x8 a[4], b[4];
#pragma unroll
      for (int mi = 0; mi < 4; mi++)
        a[mi] = *(const bf16x8*)&zt[mi * 16 + l15][kk + q * 8];
      const bf16* wp = &W1B[(size_t)(((kk >> 5) * 4 + q) * 256 + w * 64 + l15) * 8];
#pragma unroll
      for (int ni = 0; ni < 4; ni++)
        b[ni] = *(const bf16x8*)&wp[ni * 128];
#pragma unroll
      for (int mi = 0; mi < 4; mi++)
#pragma unroll
        for (int ni = 0; ni < 4; ni++)
          acc1[mi][ni] = __builtin_amdgcn_mfma_f32_16x16x32_bf16(a[mi], b[ni], acc1[mi][ni], 0, 0, 0);
    }
#pragma unroll
    for (int ni = 0; ni < 4; ni++) {
      int n = w * 64 + ni * 16 + l15;
      float bb = b1[n];
#pragma unroll
      for (int mi = 0; mi < 4; mi++)
#pragma unroll
        for (int r = 0; r < 4; r++) {
          float h = acc1[mi][ni][r] + bb;
          ht[mi * 16 + q * 4 + r][n] = (bf16)(h > 0.f ? h : 0.f);
        }
    }
  }
  __syncthreads();

  // ---- GEMM2: acc2 = H @ W2; wave w owns n in [48w, 48w+48) ----
  f32x4 acc2[4][3];
  {
    f32x4 z4 = {0.f, 0.f, 0.f, 0.f};
#pragma unroll
    for (int mi = 0; mi < 4; mi++)
#pragma unroll
      for (int ni = 0; ni < 3; ni++) acc2[mi][ni] = z4;
#pragma unroll 2
    for (int kk = 0; kk < 256; kk += 32) {
      bf16x8 a[4], b[3];
#pragma unroll
      for (int mi = 0; mi < 4; mi++)
        a[mi] = *(const bf16x8*)&ht[mi * 16 + l15][kk + q * 8];
      const bf16* wp = &W2B[(size_t)(((kk >> 5) * 4 + q) * 192 + w * 48 + l15) * 8];
#pragma unroll
      for (int ni = 0; ni < 3; ni++)
        b[ni] = *(const bf16x8*)&wp[ni * 128];
#pragma unroll
      for (int mi = 0; mi < 4; mi++)
#pragma unroll
        for (int ni = 0; ni < 3; ni++)
          acc2[mi][ni] = __builtin_amdgcn_mfma_f32_16x16x32_bf16(a[mi], b[ni], acc2[mi][ni], 0, 0, 0);
    }
  }

  // ---- epilogue: v = z + acc2 + b2, in-place in zt (wave-private cols) ----
  {
    float nrm[4][4];
#pragma unroll
    for (int mi = 0; mi < 4; mi++)
#pragma unroll
      for (int r = 0; r < 4; r++) nrm[mi][r] = 0.f;
#pragma unroll
    for (int ni = 0; ni < 3; ni++) {
      int n = w * 48 + ni * 16 + l15;
      float bb = b2[n];
#pragma unroll
      for (int mi = 0; mi < 4; mi++)
#pragma unroll
        for (int r = 0; r < 4; r++) {
          int rr = mi * 16 + q * 4 + r;
          float v = (float)zt[rr][n] + acc2[mi][ni][r] + bb;
          zt[rr][n] = (bf16)v;
          nrm[mi][r] += v * v;
        }
    }
#pragma unroll
    for (int mi = 0; mi < 4; mi++)
#pragma unroll
      for (int r = 0; r < 4; r++) {
        float s = nrm[mi][r];
        s += __shfl_xor(s, 1);
        s += __shfl_xor(s, 2);
        s += __shfl_xor(s, 4);
        s += __shfl_xor(s, 8);
        if (l15 == 0) atomicAdd(&n2l[mi * 16 + q * 4 + r], s);
      }
  }
  __syncthreads();

  // ---- copy-out ----
  if (oeB) {
    // queries: B-plane layout oeB[(p*512 + row)*8 + j], p = col/8
    for (int cc = w; cc < 24; cc += 4) {
      bf16x8 v = *(const bf16x8*)&zt[lane][cc * 8];
      *(bf16x8*)&oeB[((size_t)cc * NQ + row0 + lane) * 8] = v;
    }
  } else {
    // candidates: row-major, fully coalesced 8B granules
    uint2* dst = (uint2*)(oe + (size_t)row0 * DIM);   // 48 uint2 per row
#pragma unroll
    for (int j = t; j < 64 * 48; j += 256) {
      int r = j / 48, cc = j - r * 48;
      dst[j] = *(const uint2*)&zt[r][cc * 4];
    }
  }
  if (t < 64) on2[row0 + t] = n2l[t];
}

// ---------------- K3: dist + exp + PV, no-max flash ----------------
// 1024 blocks x 256 thr (4 waves). Block owns 128 cands (2 chunks of 64).
// Wave owns 64 queries per qt (2 qt iters); epilogue+PV run in two 32-q
// halves through the wave-private ET tile (no barriers in qt loop).
__global__ __launch_bounds__(256, 3) void k_dist(
    const bf16* __restrict__ xeB, const float* __restrict__ x2v,
    const bf16* __restrict__ ce, const float* __restrict__ c2v,
    const float* __restrict__ cy, float* __restrict__ P) {
  __shared__ alignas(16) bf16 ct[64][200];     // chunk encodings (25.6 KB)
  __shared__ alignas(16) bf16 ET[4][32][72];   // per-wave exp tiles (18.4 KB)

  const int t = threadIdx.x;
  const int n0 = blockIdx.x * 128;
  const int lane = t & 63, w = t >> 6;
  const int l15 = lane & 15, q = lane >> 4;

  f32x4 z4 = {0.f, 0.f, 0.f, 0.f};
  f32x4 oacc[2][4];            // [qt][mi]  (64 q per qt = 4 m-tiles)
#pragma unroll
  for (int qt = 0; qt < 2; qt++)
#pragma unroll
    for (int mi = 0; mi < 4; mi++) oacc[qt][mi] = z4;

  for (int c = 0; c < 2; ++c) {
    if (c) __syncthreads();                    // prior chunk's ct reads done
    {
      int r = t >> 2, qu = t & 3;
      const uint4* src = (const uint4*)(ce + (size_t)(n0 + c * 64 + r) * DIM);
      uint4* dst = (uint4*)&ct[r][0];
#pragma unroll
      for (int i = 0; i < 6; i++) dst[qu * 6 + i] = src[qu * 6 + i];
    }
    __syncthreads();

    // per-chunk constants: candidate norms + Y B-frags (col 10 = ones -> l)
    f32x4 c2r[4];
#pragma unroll
    for (int mc = 0; mc < 4; mc++)
      c2r[mc] = *(const f32x4*)&c2v[n0 + c * 64 + mc * 16 + q * 4];
    bf16x8 yf[2];
#pragma unroll
    for (int kb = 0; kb < 2; kb++)
#pragma unroll
      for (int jj = 0; jj < 8; jj++) {
        int cand = n0 + c * 64 + kb * 32 + q * 8 + jj;
        float v = (l15 < 10) ? cy[(size_t)cand * NY + l15]
                             : (l15 == 10 ? 1.f : 0.f);
        yf[kb][jj] = (bf16)v;
      }

    for (int qt = 0; qt < 2; ++qt) {
      const int qbase = qt * 256 + w * 64;
      f32x4 acc[4][4];         // [mc][nq]
#pragma unroll
      for (int mc = 0; mc < 4; mc++)
#pragma unroll
        for (int nq = 0; nq < 4; nq++) acc[mc][nq] = z4;

      // dist GEMM: A = ct (LDS), B = xeB planes (global, L2/L3-hot)
#pragma unroll 1
      for (int kk = 0; kk < 192; kk += 32) {
        bf16x8 a[4], b[4];
#pragma unroll
        for (int mc = 0; mc < 4; mc++)
          a[mc] = *(const bf16x8*)&ct[mc * 16 + l15][kk + q * 8];
        const bf16* xp = &xeB[(size_t)(((kk >> 5) * 4 + q) * NQ + qbase + l15) * 8];
#pragma unroll
        for (int nq = 0; nq < 4; nq++)
          b[nq] = *(const bf16x8*)&xp[nq * 128];
#pragma unroll
        for (int mc = 0; mc < 4; mc++)
#pragma unroll
          for (int nq = 0; nq < 4; nq++)
            acc[mc][nq] = __builtin_amdgcn_mfma_f32_16x16x32_bf16(a[mc], b[nq], acc[mc][nq], 0, 0, 0);
      }

      float x2l[4];
#pragma unroll
      for (int nq = 0; nq < 4; nq++) x2l[nq] = x2v[qbase + nq * 16 + l15];

      // two 32-query halves: exp -> ET (wave-private) -> PV MFMA
#pragma unroll
      for (int half = 0; half < 2; ++half) {
#pragma unroll
        for (int nqh = 0; nqh < 2; ++nqh) {
          int nq = half * 2 + nqh;
#pragma unroll
          for (int mc = 0; mc < 4; mc++) {
            bf16x4 ev;
#pragma unroll
            for (int r = 0; r < 4; r++) {
              float d2 = x2l[nq] + c2r[mc][r] - 2.f * acc[mc][nq][r];
              ev[r] = (bf16)__expf(-sqrtf(fmaxf(d2, 0.f)));
            }
            *(bf16x4*)&ET[w][nqh * 16 + l15][mc * 16 + q * 4] = ev;
          }
        }
#pragma unroll
        for (int mi = 0; mi < 2; mi++)
#pragma unroll
          for (int kb = 0; kb < 2; kb++) {
            bf16x8 a = *(const bf16x8*)&ET[w][mi * 16 + l15][kb * 32 + q * 8];
            oacc[qt][half * 2 + mi] =
                __builtin_amdgcn_mfma_f32_16x16x32_bf16(a, yf[kb], oacc[qt][half * 2 + mi], 0, 0, 0);
          }
      }
    }
  }

  // write partials: P[query][slice][12] = {o[10], l, pad}
  if (l15 < 11) {
#pragma unroll
    for (int qt = 0; qt < 2; qt++)
#pragma unroll
      for (int mi = 0; mi < 4; mi++)
#pragma unroll
        for (int r = 0; r < 4; r++) {
          int query = qt * 256 + w * 64 + mi * 16 + q * 4 + r;
          P[((size_t)query * NSLICE + blockIdx.x) * 12 + l15] = oacc[qt][mi][r];
        }
  }
}

// ---------------- K4: combine (pure sum — no max needed) ----------------
__global__ __launch_bounds__(256) void k_comb(const float* __restrict__ P,
                                              float* __restrict__ out) {
  __shared__ float red[4][11];
  const int t = threadIdx.x;
  const int qy = blockIdx.x;
  const int lane = t & 63, w = t >> 6;

  float s[11];
#pragma unroll
  for (int j = 0; j < 11; j++) s[j] = 0.f;
#pragma unroll
  for (int i = 0; i < 4; i++) {
    const float* p = &P[((size_t)qy * NSLICE + t + 256 * i) * 12];
    f32x4 v0 = *(const f32x4*)&p[0];
    f32x4 v1 = *(const f32x4*)&p[4];
    f32x4 v2 = *(const f32x4*)&p[8];
#pragma unroll
    for (int j = 0; j < 4; j++) s[j] += v0[j];
#pragma unroll
    for (int j = 0; j < 4; j++) s[4 + j] += v1[j];
#pragma unroll
    for (int j = 0; j < 3; j++) s[8 + j] += v2[j];   // p[11] is pad — skip
  }
#pragma unroll
  for (int d = 1; d < 64; d <<= 1)
#pragma unroll
    for (int j = 0; j < 11; j++) s[j] += __shfl_xor(s[j], d);
  if (lane == 0)
#pragma unroll
    for (int j = 0; j < 11; j++) red[w][j] = s[j];
  __syncthreads();
  if (t < 10) {
    float o = red[0][t] + red[1][t] + red[2][t] + red[3][t];
    float l = red[0][10] + red[1][10] + red[2][10] + red[3][10];
    out[qy * NY + t] = o / l;
  }
}

// ---------------- launcher ----------------
extern "C" void kernel_launch(void* const* d_in, const int* in_sizes, int n_in,
                              void* d_out, int out_size, void* d_ws, size_t ws_size,
                              hipStream_t stream) {
  (void)in_sizes; (void)n_in; (void)out_size; (void)ws_size;
  const float* x_num = (const float*)d_in[0];
  const int*   x_cat = (const int*)d_in[1];
  const float* c_num = (const float*)d_in[2];
  const int*   c_cat = (const int*)d_in[3];
  const float* c_y   = (const float*)d_in[4];
  const float* W_num = (const float*)d_in[5];
  const float* b_num = (const float*)d_in[6];
  const float* emb   = (const float*)d_in[7];
  const float* W1    = (const float*)d_in[8];
  const float* b1    = (const float*)d_in[9];
  const float* W2    = (const float*)d_in[10];
  const float* b2    = (const float*)d_in[11];
  float* out = (float*)d_out;

  char* ws = (char*)d_ws;
  bf16*  W1B = (bf16*)(ws + OFF_W1B);
  bf16*  W2B = (bf16*)(ws + OFF_W2B);
  bf16*  xeB = (bf16*)(ws + OFF_XEB);
  float* x2v = (float*)(ws + OFF_X2);
  bf16*  ce  = (bf16*)(ws + OFF_CE);
  float* c2v = (float*)(ws + OFF_C2);
  float* P   = (float*)(ws + OFF_P);

  k_prep<<<dim3(384), dim3(256), 0, stream>>>(W1, W2, W1B, W2B);
  k_encode<<<dim3(NQ / 64), dim3(256), 0, stream>>>(
      x_num, x_cat, W_num, b_num, emb, b1, b2, W1B, W2B, nullptr, xeB, x2v);
  k_encode<<<dim3(NC / 64), dim3(256), 0, stream>>>(
      c_num, c_cat, W_num, b_num, emb, b1, b2, W1B, W2B, ce, nullptr, c2v);
  k_dist<<<dim3(NSLICE), dim3(256), 0, stream>>>(xeB, x2v, ce, c2v, c_y, P);
  k_comb<<<dim3(NQ), dim3(256), 0, stream>>>(P, out);
}

// Round 6
// 217.638 us; speedup vs baseline: 1.7358x; 1.0204x over previous
//
#include <hip/hip_runtime.h>
#include <hip/hip_bf16.h>

// ModernNCA fused bf16-MFMA pipeline, v6.
// B=512 queries, N=131072 candidates, D=192, H=256, NY=10.
// v6: k_dist query-split blocks (256c x 256q) to cut per-wave registers
// (acc 32 + oacc 16 AGPR, ~118 total) -> 4 waves/SIMD; c2 via LDS; ET 16
// rows. k_encode hidden processed in 2 halves -> 43 KB LDS, 3 blocks/CU.
typedef __bf16 bf16;
typedef __attribute__((ext_vector_type(8))) __bf16 bf16x8;
typedef __attribute__((ext_vector_type(4))) __bf16 bf16x4;
typedef __attribute__((ext_vector_type(4))) float f32x4;

#define NQ     512
#define NC     131072
#define DIM    192
#define HID    256
#define NY     10
#define NSLICE 512           // cand slices of 256; k_dist grid = 2*NSLICE

// ---------------- workspace layout (bytes) ----------------
#define OFF_W1B 0u                              // 24 planes x 256 x 8 bf16 = 98304
#define OFF_W2B (OFF_W1B + 98304u)              // 32 planes x 192 x 8 bf16 = 98304
#define OFF_XEB (OFF_W2B + 98304u)              // 24 planes x 512 x 8 bf16 = 196608
#define OFF_X2  (OFF_XEB + 196608u)             // 512 f32 = 2048
#define OFF_CE  (OFF_X2 + 2048u)                // 131072x192 bf16 = 50331648
#define OFF_C2  (OFF_CE + 50331648u)            // 131072 f32 = 524288
#define OFF_P   (OFF_C2 + 524288u)              // 512x512x12 f32 = 12582912

// ---------------- K0: weight cast into B-fragment plane layout ----------
// Plane p = (k>>5)*4 + ((k>>3)&3); element j = k&7.
__global__ __launch_bounds__(256) void k_prep(const float* __restrict__ W1,
                                              const float* __restrict__ W2,
                                              bf16* __restrict__ W1B,
                                              bf16* __restrict__ W2B) {
  int idx = blockIdx.x * 256 + threadIdx.x;   // 0..98303
  if (idx < 192 * 256) {
    int k = idx / 256, n = idx % 256;
    int p = (k >> 5) * 4 + ((k >> 3) & 3);
    W1B[((size_t)(p * 256 + n)) * 8 + (k & 7)] = (bf16)W1[idx];
  } else {
    int i2 = idx - 192 * 256;
    int k = i2 / 192, n = i2 % 192;
    int p = (k >> 5) * 4 + ((k >> 3) & 3);
    W2B[((size_t)(p * 192 + n)) * 8 + (k & 7)] = (bf16)W2[i2];
  }
}

// ---------------- K1/K2: encode + residual MLP (256 thr, 64 rows) --------
// Encode: wave w owns features {2w,2w+1} + cat w. Hidden processed in 2
// halves of 128 cols (hth 17.4 KB): GEMM1-half (wave w owns 32 local cols)
// -> barrier -> GEMM2 partial accumulate. LDS 43 KB -> 3 blocks/CU.
__global__ __launch_bounds__(256, 3) void k_encode(
    const float* __restrict__ xn, const int* __restrict__ xc,
    const float* __restrict__ Wn, const float* __restrict__ bn,
    const float* __restrict__ emb, const float* __restrict__ b1,
    const float* __restrict__ b2, const bf16* __restrict__ W1B,
    const bf16* __restrict__ W2B, bf16* __restrict__ oe,
    bf16* __restrict__ oeB, float* __restrict__ on2) {
  __shared__ alignas(16) bf16 zt[64][200];    // encoded z / output (25.6 KB)
  __shared__ alignas(16) bf16 hth[64][136];   // hidden half (17.4 KB)
  __shared__ float n2l[64];

  const int t = threadIdx.x;
  const int row0 = blockIdx.x * 64;
  const int lane = t & 63, w = t >> 6;       // wave 0..3
  const int l15 = lane & 15, q = lane >> 4;

  if (t < 64) n2l[t] = 0.f;

  // ---- encode: wave w -> num features {2w,2w+1} + cat feature w ----
  {
    const int g = row0 + lane;
    float2 xv2 = *(const float2*)&xn[(size_t)g * 8 + 2 * w];
    int cv = xc[g * 4 + w];
#pragma unroll
    for (int f01 = 0; f01 < 2; f01++) {
      int f = 2 * w + f01;
      float xv = f01 ? xv2.y : xv2.x;
      f32x4 wv[4], bv[4];
#pragma unroll
      for (int i = 0; i < 4; i++) {
        wv[i] = *(const f32x4*)&Wn[f * 16 + i * 4];
        bv[i] = *(const f32x4*)&bn[f * 16 + i * 4];
      }
      bf16x8 p0, p1;
#pragma unroll
      for (int u = 0; u < 8; u++) {
        p0[u] = (bf16)(xv * wv[u >> 2][u & 3] + bv[u >> 2][u & 3]);
        p1[u] = (bf16)(xv * wv[2 + (u >> 2)][u & 3] + bv[2 + (u >> 2)][u & 3]);
      }
      *(bf16x8*)&zt[lane][f * 16] = p0;
      *(bf16x8*)&zt[lane][f * 16 + 8] = p1;
    }
    const float* er = &emb[(size_t)(w * 100 + cv) * 16];
    f32x4 e0 = *(const f32x4*)&er[0];
    f32x4 e1 = *(const f32x4*)&er[4];
    f32x4 e2 = *(const f32x4*)&er[8];
    f32x4 e3 = *(const f32x4*)&er[12];
    bf16x8 pc0, pc1;
#pragma unroll
    for (int u = 0; u < 4; u++) {
      pc0[u] = (bf16)e0[u]; pc0[4 + u] = (bf16)e1[u];
      pc1[u] = (bf16)e2[u]; pc1[4 + u] = (bf16)e3[u];
    }
    *(bf16x8*)&zt[lane][128 + w * 16] = pc0;
    *(bf16x8*)&zt[lane][128 + w * 16 + 8] = pc1;
  }
  __syncthreads();

  f32x4 z4 = {0.f, 0.f, 0.f, 0.f};
  f32x4 acc2[4][3];
#pragma unroll
  for (int mi = 0; mi < 4; mi++)
#pragma unroll
    for (int ni = 0; ni < 3; ni++) acc2[mi][ni] = z4;

#pragma unroll 1
  for (int h = 0; h < 2; ++h) {
    if (h) __syncthreads();        // prior GEMM2 reads of hth done

    // ---- GEMM1 half: wave w owns local cols [w*32, w*32+32) ----
    {
      f32x4 acc1[4][2];
#pragma unroll
      for (int mi = 0; mi < 4; mi++)
#pragma unroll
        for (int ni = 0; ni < 2; ni++) acc1[mi][ni] = z4;
#pragma unroll 2
      for (int kk = 0; kk < 192; kk += 32) {
        bf16x8 a[4], b[2];
#pragma unroll
        for (int mi = 0; mi < 4; mi++)
          a[mi] = *(const bf16x8*)&zt[mi * 16 + l15][kk + q * 8];
        const bf16* wp = &W1B[(size_t)(((kk >> 5) * 4 + q) * 256 + h * 128 + w * 32 + l15) * 8];
#pragma unroll
        for (int ni = 0; ni < 2; ni++)
          b[ni] = *(const bf16x8*)&wp[ni * 128];
#pragma unroll
        for (int mi = 0; mi < 4; mi++)
#pragma unroll
          for (int ni = 0; ni < 2; ni++)
            acc1[mi][ni] = __builtin_amdgcn_mfma_f32_16x16x32_bf16(a[mi], b[ni], acc1[mi][ni], 0, 0, 0);
      }
#pragma unroll
      for (int ni = 0; ni < 2; ni++) {
        int nl = w * 32 + ni * 16 + l15;
        float bb = b1[h * 128 + nl];
#pragma unroll
        for (int mi = 0; mi < 4; mi++)
#pragma unroll
          for (int r = 0; r < 4; r++) {
            float hv = acc1[mi][ni][r] + bb;
            hth[mi * 16 + q * 4 + r][nl] = (bf16)(hv > 0.f ? hv : 0.f);
          }
      }
    }
    __syncthreads();

    // ---- GEMM2 partial: k in [h*128, h*128+128); wave w owns n [48w,48w+48) --
#pragma unroll 2
    for (int kk2 = 0; kk2 < 128; kk2 += 32) {
      bf16x8 a[4], b[3];
#pragma unroll
      for (int mi = 0; mi < 4; mi++)
        a[mi] = *(const bf16x8*)&hth[mi * 16 + l15][kk2 + q * 8];
      const bf16* wp = &W2B[(size_t)(((h * 4 + (kk2 >> 5)) * 4 + q) * 192 + w * 48 + l15) * 8];
#pragma unroll
      for (int ni = 0; ni < 3; ni++)
        b[ni] = *(const bf16x8*)&wp[ni * 128];
#pragma unroll
      for (int mi = 0; mi < 4; mi++)
#pragma unroll
        for (int ni = 0; ni < 3; ni++)
          acc2[mi][ni] = __builtin_amdgcn_mfma_f32_16x16x32_bf16(a[mi], b[ni], acc2[mi][ni], 0, 0, 0);
    }
  }

  // ---- epilogue: v = z + acc2 + b2, in-place in zt (wave-private cols) ----
  {
    float nrm[4][4];
#pragma unroll
    for (int mi = 0; mi < 4; mi++)
#pragma unroll
      for (int r = 0; r < 4; r++) nrm[mi][r] = 0.f;
#pragma unroll
    for (int ni = 0; ni < 3; ni++) {
      int n = w * 48 + ni * 16 + l15;
      float bb = b2[n];
#pragma unroll
      for (int mi = 0; mi < 4; mi++)
#pragma unroll
        for (int r = 0; r < 4; r++) {
          int rr = mi * 16 + q * 4 + r;
          float v = (float)zt[rr][n] + acc2[mi][ni][r] + bb;
          zt[rr][n] = (bf16)v;
          nrm[mi][r] += v * v;
        }
    }
#pragma unroll
    for (int mi = 0; mi < 4; mi++)
#pragma unroll
      for (int r = 0; r < 4; r++) {
        float s = nrm[mi][r];
        s += __shfl_xor(s, 1);
        s += __shfl_xor(s, 2);
        s += __shfl_xor(s, 4);
        s += __shfl_xor(s, 8);
        if (l15 == 0) atomicAdd(&n2l[mi * 16 + q * 4 + r], s);
      }
  }
  __syncthreads();

  // ---- copy-out ----
  if (oeB) {
    // queries: B-plane layout oeB[(p*512 + row)*8 + j], p = col/8
    for (int cc = w; cc < 24; cc += 4) {
      bf16x8 v = *(const bf16x8*)&zt[lane][cc * 8];
      *(bf16x8*)&oeB[((size_t)cc * NQ + row0 + lane) * 8] = v;
    }
  } else {
    // candidates: row-major, fully coalesced 8B granules
    uint2* dst = (uint2*)(oe + (size_t)row0 * DIM);   // 48 uint2 per row
#pragma unroll
    for (int j = t; j < 64 * 48; j += 256) {
      int r = j / 48, cc = j - r * 48;
      dst[j] = *(const uint2*)&zt[r][cc * 4];
    }
  }
  if (t < 64) on2[row0 + t] = n2l[t];
}

// ---------------- K3: dist + exp + PV, no-max flash ----------------
// Grid 1024 = 512 cand-slices x 2 query-halves; block = 256 cands x 256 q.
// 256 thr (4 waves); wave owns 32 queries per qt (qt=2); 4 chunks of 64
// cands. Per-wave regs ~118 (acc 32 + oacc 16 AGPR) -> 4 waves/SIMD; LDS
// 35 KB -> 4 blocks/CU. Blocks b and b+512 share cand data + XCD (b%8).
__global__ __launch_bounds__(256, 4) void k_dist(
    const bf16* __restrict__ xeB, const float* __restrict__ x2v,
    const bf16* __restrict__ ce, const float* __restrict__ c2v,
    const float* __restrict__ cy, float* __restrict__ P) {
  __shared__ alignas(16) bf16 ct[64][200];     // chunk encodings (25.6 KB)
  __shared__ alignas(16) bf16 ET[4][16][72];   // per-wave exp tiles (9.2 KB)
  __shared__ float c2l[64];

  const int t = threadIdx.x;
  const int slice = blockIdx.x & (NSLICE - 1);
  const int half = blockIdx.x >> 9;
  const int n0 = slice * 256;
  const int qh = half * 256;
  const int lane = t & 63, w = t >> 6;
  const int l15 = lane & 15, q = lane >> 4;

  f32x4 z4 = {0.f, 0.f, 0.f, 0.f};
  f32x4 oacc[2][2];            // [qt][nq] — accumulates across the 4 chunks
#pragma unroll
  for (int qt = 0; qt < 2; qt++)
#pragma unroll
    for (int nq = 0; nq < 2; nq++) oacc[qt][nq] = z4;

#pragma unroll 1
  for (int c = 0; c < 4; ++c) {
    if (c) __syncthreads();                    // prior chunk's ct/c2l reads done
    {
      int r = t >> 2, qu = t & 3;
      const uint4* src = (const uint4*)(ce + (size_t)(n0 + c * 64 + r) * DIM);
      uint4* dst = (uint4*)&ct[r][0];
#pragma unroll
      for (int i = 0; i < 6; i++) dst[qu * 6 + i] = src[qu * 6 + i];
    }
    if (t < 16) *(f32x4*)&c2l[t * 4] = *(const f32x4*)&c2v[n0 + c * 64 + t * 4];
    __syncthreads();

    // Y B-frags for this chunk (col 10 = ones -> l)
    bf16x8 yf[2];
#pragma unroll
    for (int kb = 0; kb < 2; kb++)
#pragma unroll
      for (int jj = 0; jj < 8; jj++) {
        int cand = n0 + c * 64 + kb * 32 + q * 8 + jj;
        float v = (l15 < 10) ? cy[(size_t)cand * NY + l15]
                             : (l15 == 10 ? 1.f : 0.f);
        yf[kb][jj] = (bf16)v;
      }

#pragma unroll 1
    for (int qt = 0; qt < 2; ++qt) {
      const int qbase = qh + qt * 128 + w * 32;
      f32x4 acc[4][2];         // [mc][nq]
#pragma unroll
      for (int mc = 0; mc < 4; mc++)
#pragma unroll
        for (int nq = 0; nq < 2; nq++) acc[mc][nq] = z4;

      // dist GEMM: A = ct (LDS), B = xeB planes (global, L2-hot)
#pragma unroll 1
      for (int kk = 0; kk < 192; kk += 32) {
        bf16x8 a[4], b[2];
#pragma unroll
        for (int mc = 0; mc < 4; mc++)
          a[mc] = *(const bf16x8*)&ct[mc * 16 + l15][kk + q * 8];
        const bf16* xp = &xeB[(size_t)(((kk >> 5) * 4 + q) * NQ + qbase + l15) * 8];
#pragma unroll
        for (int nq = 0; nq < 2; nq++)
          b[nq] = *(const bf16x8*)&xp[nq * 128];
#pragma unroll
        for (int mc = 0; mc < 4; mc++)
#pragma unroll
          for (int nq = 0; nq < 2; nq++)
            acc[mc][nq] = __builtin_amdgcn_mfma_f32_16x16x32_bf16(a[mc], b[nq], acc[mc][nq], 0, 0, 0);
      }

      float x2l[2];
#pragma unroll
      for (int nq = 0; nq < 2; nq++) x2l[nq] = x2v[qbase + nq * 16 + l15];

      // per 16-query group: exp -> ET (wave-private 16 rows) -> PV MFMA
#pragma unroll
      for (int nq = 0; nq < 2; ++nq) {
#pragma unroll
        for (int mc = 0; mc < 4; mc++) {
          f32x4 cc = *(const f32x4*)&c2l[mc * 16 + q * 4];
          f32x4 s4;
#pragma unroll
          for (int r = 0; r < 4; r++) s4[r] = x2l[nq] + cc[r];
          bf16x4 ev;
#pragma unroll
          for (int r = 0; r < 4; r++) {
            float d2 = __builtin_fmaf(-2.f, acc[mc][nq][r], s4[r]);
            ev[r] = (bf16)__expf(-sqrtf(__builtin_fabsf(d2)));
          }
          *(bf16x4*)&ET[w][l15][mc * 16 + q * 4] = ev;
        }
#pragma unroll
        for (int kb = 0; kb < 2; kb++) {
          bf16x8 a = *(const bf16x8*)&ET[w][l15][kb * 32 + q * 8];
          oacc[qt][nq] = __builtin_amdgcn_mfma_f32_16x16x32_bf16(a, yf[kb], oacc[qt][nq], 0, 0, 0);
        }
      }
    }
  }

  // write partials: P[query][slice][12] = {o[10], l, pad}
  if (l15 < 11) {
#pragma unroll
    for (int qt = 0; qt < 2; qt++)
#pragma unroll
      for (int nq = 0; nq < 2; nq++)
#pragma unroll
        for (int r = 0; r < 4; r++) {
          int query = qh + qt * 128 + w * 32 + nq * 16 + q * 4 + r;
          P[((size_t)query * NSLICE + slice) * 12 + l15] = oacc[qt][nq][r];
        }
  }
}

// ---------------- K4: combine (pure sum — no max needed) ----------------
__global__ __launch_bounds__(512) void k_comb(const float* __restrict__ P,
                                              float* __restrict__ out) {
  __shared__ float red[8][11];
  const int t = threadIdx.x;
  const int qy = blockIdx.x;
  const int lane = t & 63, w = t >> 6;

  const float* p = &P[((size_t)qy * NSLICE + t) * 12];
  f32x4 v0 = *(const f32x4*)&p[0];
  f32x4 v1 = *(const f32x4*)&p[4];
  f32x4 v2 = *(const f32x4*)&p[8];
  float s[11];
#pragma unroll
  for (int j = 0; j < 4; j++) s[j] = v0[j];
#pragma unroll
  for (int j = 0; j < 4; j++) s[4 + j] = v1[j];
#pragma unroll
  for (int j = 0; j < 3; j++) s[8 + j] = v2[j];
#pragma unroll
  for (int d = 1; d < 64; d <<= 1)
#pragma unroll
    for (int j = 0; j < 11; j++) s[j] += __shfl_xor(s[j], d);
  if (lane == 0)
#pragma unroll
    for (int j = 0; j < 11; j++) red[w][j] = s[j];
  __syncthreads();
  if (t < 10) {
    float o = 0.f, l = 0.f;
#pragma unroll
    for (int i = 0; i < 8; i++) { o += red[i][t]; l += red[i][10]; }
    out[qy * NY + t] = o / l;
  }
}

// ---------------- launcher ----------------
extern "C" void kernel_launch(void* const* d_in, const int* in_sizes, int n_in,
                              void* d_out, int out_size, void* d_ws, size_t ws_size,
                              hipStream_t stream) {
  (void)in_sizes; (void)n_in; (void)out_size; (void)ws_size;
  const float* x_num = (const float*)d_in[0];
  const int*   x_cat = (const int*)d_in[1];
  const float* c_num = (const float*)d_in[2];
  const int*   c_cat = (const int*)d_in[3];
  const float* c_y   = (const float*)d_in[4];
  const float* W_num = (const float*)d_in[5];
  const float* b_num = (const float*)d_in[6];
  const float* emb   = (const float*)d_in[7];
  const float* W1    = (const float*)d_in[8];
  const float* b1    = (const float*)d_in[9];
  const float* W2    = (const float*)d_in[10];
  const float* b2    = (const float*)d_in[11];
  float* out = (float*)d_out;

  char* ws = (char*)d_ws;
  bf16*  W1B = (bf16*)(ws + OFF_W1B);
  bf16*  W2B = (bf16*)(ws + OFF_W2B);
  bf16*  xeB = (bf16*)(ws + OFF_XEB);
  float* x2v = (float*)(ws + OFF_X2);
  bf16*  ce  = (bf16*)(ws + OFF_CE);
  float* c2v = (float*)(ws + OFF_C2);
  float* P   = (float*)(ws + OFF_P);

  k_prep<<<dim3(384), dim3(256), 0, stream>>>(W1, W2, W1B, W2B);
  k_encode<<<dim3(NQ / 64), dim3(256), 0, stream>>>(
      x_num, x_cat, W_num, b_num, emb, b1, b2, W1B, W2B, nullptr, xeB, x2v);
  k_encode<<<dim3(NC / 64), dim3(256), 0, stream>>>(
      c_num, c_cat, W_num, b_num, emb, b1, b2, W1B, W2B, ce, nullptr, c2v);
  k_dist<<<dim3(2 * NSLICE), dim3(256), 0, stream>>>(xeB, x2v, ce, c2v, c_y, P);
  k_comb<<<dim3(NQ), dim3(512), 0, stream>>>(P, out);
}